// Round 6
// baseline (178.295 us; speedup 1.0000x reference)
//
#include <hip/hip_runtime.h>
#include <math.h>

#define INV_TAU 1000.0f
#define TEMP    0.1f
#define CEXP    -1442.6950408889634f   // -1000 * log2(e)
#define SQRTC   37.98283767f           // sqrt(1000 * log2(e))

// Problem: B=2,H=8 -> BH=16; N=256; L=64.  X,Y: [BH,256,64] f32. out: [BH,256,256] f32.
//
// Round 16: exp2-count reduction via rank-banded EV staging. tau=0.001 =>
// any entry with |rank(y_k) - i| > ~50 is an exact f16 zero (arg < -30).
// prep's bitonic sort carries the original index (tie-broken: strict (key,idx)
// order) and packs it into lzV's low 8 mantissa bits (<=1e-4 rel, no ws
// growth). pass1 EV staging slots are RANK-ordered: slot t stages the row
// ranked t (scale = -nssV[t] exactly, LDS row = packed idx); each wave covers
// 64 consecutive ranks -> oct band test is wave-uniform -> skip ~28% of EV
// octs (zeros stored, 8 exp2 + 4 pk-fma elided). EU unchanged. + setprio(1)
// around MFMA cluster (T5, independent 2-block regime).
//
// ws (floats): cost[1048576] | nssu|lziu|nssv|lziv (262144 ea) |
//              parts[2048] | gamma u32x4[2048 chunks x 64 l x 64 lanes] (134MB)

typedef __attribute__((ext_vector_type(8))) _Float16 half8;
typedef __attribute__((ext_vector_type(8))) short short8;
typedef __attribute__((ext_vector_type(4))) float f32x4;
typedef __attribute__((ext_vector_type(2))) float f32x2;
typedef __attribute__((ext_vector_type(4))) unsigned int u32x4;

__device__ __forceinline__ float fexp2(float x) { return __builtin_amdgcn_exp2f(x); }

__device__ __forceinline__ half8 ldsh8(const unsigned short* p) {
  return __builtin_bit_cast(half8, *(const short8*)p);
}

// dst[15:0]=bf16(lo), dst[31:16]=bf16(hi), RNE
__device__ __forceinline__ unsigned cvt_pk_bf16(float lo, float hi) {
  unsigned r;
  asm("v_cvt_pk_bf16_f32 %0, %1, %2" : "=v"(r) : "v"(lo), "v"(hi));
  return r;
}

// swizzled short-offset of (row, oct g) in a 32-short-per-row table
__device__ __forceinline__ int tswz(int row, int g) {
  return row * 32 + (((g + (row >> 1)) & 3) << 3);
}

// prep: blockIdx.x < 1024 -> cost quad-row tile; else sortz for (l, bh, X/Y).
// sortz: index-payload bitonic sort (ascending (key,idx)); outputs per
// descending-rank i: nss[i] = -SQRTC*s_i, lz[i] = -log2(Z_i) (banded Z);
// for the V side, lz's low 8 mantissa bits carry the original row index.
__global__ __launch_bounds__(256) void prep_kernel(const float* __restrict__ X,
                                                   const float* __restrict__ Y,
                                                   float* __restrict__ cost,
                                                   float* __restrict__ nssu, float* __restrict__ lziu,
                                                   float* __restrict__ nssv, float* __restrict__ lziv) {
  __shared__ __align__(16) float smem[512];
  const int tid = threadIdx.x;
  if (blockIdx.x < 1024) {
    const int jq = blockIdx.x & 63, bh = blockIdx.x >> 6;
    const int j0 = jq * 4;
    smem[tid] = X[((size_t)bh*256 + j0 + (tid >> 6))*64 + (tid & 63)];
    __syncthreads();
    const float4* yp = (const float4*)(Y + ((size_t)bh*256 + tid)*64);
    float dot[4] = {0.f,0.f,0.f,0.f}, x2[4] = {0.f,0.f,0.f,0.f}, y2 = 0.f;
#pragma unroll
    for (int t = 0; t < 16; ++t) {
      float4 yv = yp[t];
      y2 += yv.x*yv.x + yv.y*yv.y + yv.z*yv.z + yv.w*yv.w;
#pragma unroll
      for (int r = 0; r < 4; ++r) {
        float4 xv = ((const float4*)(smem + r*64))[t];
        dot[r] += xv.x*yv.x + xv.y*yv.y + xv.z*yv.z + xv.w*yv.w;
        x2[r]  += xv.x*xv.x + xv.y*xv.y + xv.z*xv.z + xv.w*xv.w;
      }
    }
#pragma unroll
    for (int r = 0; r < 4; ++r) {
      float c = x2[r] + y2 - 2.f*dot[r];
      cost[((size_t)bh*256 + j0 + r)*256 + tid] = sqrtf(fmaxf(c, 1e-12f));
    }
  } else {
    const int bidx = blockIdx.x - 1024;
    const int l = bidx & 63, bh = (bidx >> 6) & 15, uv = bidx >> 10;
    const float* S = uv ? Y : X;
    float* so = uv ? nssv : nssu;
    float* zo = uv ? lziv : lziu;
    const float v = S[((size_t)bh*256 + tid)*64 + l];
    // order-preserving key (unsigned-ascending) + index payload
    unsigned u = __float_as_uint(v);
    unsigned k = ((int)u < 0) ? ~u : (u | 0x80000000u);
    unsigned id = (unsigned)tid;
#pragma unroll
    for (int kk = 2; kk <= 256; kk <<= 1) {
#pragma unroll
      for (int j = kk >> 1; j > 0; j >>= 1) {
        unsigned ok, oi;
        if (j >= 64) {
          smem[tid] = __uint_as_float(k);
          smem[256 + tid] = __uint_as_float(id);
          __syncthreads();
          ok = __float_as_uint(smem[tid ^ j]);
          oi = __float_as_uint(smem[256 + (tid ^ j)]);
          __syncthreads();
        } else {
          ok = (unsigned)__shfl_xor((int)k, j, 64);
          oi = (unsigned)__shfl_xor((int)id, j, 64);
        }
        const bool keepmin = ((tid & kk) == 0) == ((tid & j) == 0);
        const bool iless = (k < ok) | ((k == ok) & (id < oi));  // strict order
        const bool take_other = keepmin ? (!iless) : iless;
        k  = take_other ? ok : k;
        id = take_other ? oi : id;
      }
    }
    // untransform key -> value; thread holds ascending position tid
    const unsigned su = (k & 0x80000000u) ? (k ^ 0x80000000u) : ~k;
    const float sval = __uint_as_float(su);
    smem[tid] = sval;
    __syncthreads();
    // banded Z around own ascending position
    int lo = tid > 48 ? tid - 48 : 0;
    const int hi = tid < 207 ? tid + 48 : 255;
    lo &= ~1;
    f32x2 z2 = {0.f, 0.f};
    const f32x2 svv = {sval, sval};
    const f32x2 cxx = {CEXP, CEXP};
    for (int p = lo; p <= hi; p += 2) {
      f32x2 s2 = *(const f32x2*)(smem + p);
      f32x2 d  = s2 - svv;
      f32x2 a  = (d * d) * cxx;
      z2 += (f32x2){fexp2(a.x), fexp2(a.y)};
    }
    const float z = z2.x + z2.y;
    const int rank = 255 - tid;                     // descending rank
    const int base = (bh*64 + l)*256 + rank;
    so[base] = -SQRTC * sval;
    const float lzv = -__log2f(z);
    if (uv) {
      unsigned b = (__float_as_uint(lzv) & 0xFFFFFF00u) | id;
      zo[base] = __uint_as_float(b);
    } else {
      zo[base] = lzv;
    }
  }
}

// one oct of 8 exp entries: d = sc + nss_i (pk add); arg = -d*d + lz_i
// (pk fma); e = exp2(arg); packed to 8 f16.
__device__ __forceinline__ u32x4 oct_exp(const float* __restrict__ nss,
                                         const float* __restrict__ lz, float sc) {
  const f32x2 sc2 = {sc, sc};
  f32x2 d0 = sc2 + *(const f32x2*)(nss + 0);
  f32x2 d1 = sc2 + *(const f32x2*)(nss + 2);
  f32x2 d2 = sc2 + *(const f32x2*)(nss + 4);
  f32x2 d3 = sc2 + *(const f32x2*)(nss + 6);
  f32x2 a0 = __builtin_elementwise_fma(-d0, d0, *(const f32x2*)(lz + 0));
  f32x2 a1 = __builtin_elementwise_fma(-d1, d1, *(const f32x2*)(lz + 2));
  f32x2 a2 = __builtin_elementwise_fma(-d2, d2, *(const f32x2*)(lz + 4));
  f32x2 a3 = __builtin_elementwise_fma(-d3, d3, *(const f32x2*)(lz + 6));
  u32x4 w;
  w[0] = __builtin_bit_cast(unsigned, __builtin_amdgcn_cvt_pkrtz(fexp2(a0.x), fexp2(a0.y)));
  w[1] = __builtin_bit_cast(unsigned, __builtin_amdgcn_cvt_pkrtz(fexp2(a1.x), fexp2(a1.y)));
  w[2] = __builtin_bit_cast(unsigned, __builtin_amdgcn_cvt_pkrtz(fexp2(a2.x), fexp2(a2.y)));
  w[3] = __builtin_bit_cast(unsigned, __builtin_amdgcn_cvt_pkrtz(fexp2(a3.x), fexp2(a3.y)));
  return w;
}

// stage one 32-i slab (512 threads):
// EU (input-order rows): thread t -> row t&127, oct t>>7.
// EV (RANK-order slots): slot rt = t&255 stages the row ranked rt
// (row = vrow from lzV idx bits, scale = -nssV[rt]); octs (t>>8)*2+{0,1}.
// Wave covers ranks [rmin, rmin+63] -> oct band test is wave-uniform;
// out-of-band octs store zeros (entries are exact f16 zeros).
__device__ __forceinline__ void stage_slab(int t, int ib, float usc,
                                           float vscR, int vrow, int rmin,
                                           const float* __restrict__ nssU, const float* __restrict__ lzU,
                                           const float* __restrict__ nssV, const float* __restrict__ lzV,
                                           unsigned short* __restrict__ EU,
                                           unsigned short* __restrict__ EV) {
  {
    const int r = t & 127, g = t >> 7;
    const int i0 = ib + (g << 3);
    *(u32x4*)&EU[tswz(r, g)] = oct_exp(nssU + i0, lzU + i0, usc);
  }
  {
    const int gp = (t >> 8) << 1;
#pragma unroll
    for (int gg = 0; gg < 2; ++gg) {
      const int g = gp + gg;
      const int i0 = ib + (g << 3);
      const int off = tswz(vrow, g);
      if (i0 + 7 < rmin - 56 || i0 > rmin + 63 + 56) {
        *(u32x4*)&EV[off] = (u32x4){0u, 0u, 0u, 0u};
      } else {
        *(u32x4*)&EV[off] = oct_exp(nssV + i0, lzV + i0, vscR);
      }
    }
  }
}

// Pass 1: per (strip sb, l, bh): 128j x 256k Gamma strip via pipelined fp16
// MFMA (8 waves, 64x64 wave tiles, acc[16]); dot with cost -> parts; Gamma
// bf16 NT-stored as u32x4 fragment-PAIRS.
__global__ __launch_bounds__(512, 4) void pass1_kernel(
    const float* __restrict__ X, const float* __restrict__ Y,
    const float* __restrict__ cost,
    const float* __restrict__ nssu, const float* __restrict__ lziu,
    const float* __restrict__ nssv, const float* __restrict__ lziv,
    float* __restrict__ parts, u32x4* __restrict__ gamma) {
  const int sb = blockIdx.x, l = blockIdx.y, bh = blockIdx.z;
  const int j0 = sb * 128;
  const int tid = threadIdx.x, wave = tid >> 6, lane = tid & 63;
  const int wj = (wave & 1) * 64, wk = (wave >> 1) * 64;
  const int m = lane & 15, q = lane >> 4;
  const int inner = m*32 + (((q + (m >> 1)) & 3) << 3);

  __shared__ __align__(16) float nssU[256], lzU[256], nssV[256], lzV[256];
  __shared__ __align__(16) unsigned short EU0[128*32], EU1[128*32];
  __shared__ __align__(16) unsigned short EV0[256*32], EV1[256*32];
  __shared__ float red[8];
  // LDS: 4KB + 16KB + 32KB = 52.2KB -> 2 blocks/CU x 8 waves

  const int lb = (bh*64 + l)*256;
  const float usc = SQRTC * X[((size_t)bh*256 + j0 + (tid & 127))*64 + l];
  if (tid < 256) { nssU[tid] = nssu[lb + tid]; lzU[tid] = lziu[lb + tid]; }
  else { const int t2 = tid - 256; nssV[t2] = nssv[lb + t2]; lzV[t2] = lziv[lb + t2]; }

  f32x4 acc[16];
#pragma unroll
  for (int t = 0; t < 16; ++t) acc[t] = (f32x4){0.f, 0.f, 0.f, 0.f};

  __syncthreads();
  // rank-slot EV staging params (tables now visible)
  const int rt = tid & 255;
  const float vscR = -nssV[rt];                       // == SQRTC * Y[vrow] exactly
  const int vrow = (int)(__float_as_uint(lzV[rt]) & 0xFFu);
  const int rmin = ((tid >> 6) & 3) * 64;

  stage_slab(tid, 0, usc, vscR, vrow, rmin, nssU, lzU, nssV, lzV, EU0, EV0);
  __syncthreads();
#pragma unroll 1
  for (int s = 0; s < 8; ++s) {
    const unsigned short* EUc = (s & 1) ? EU1 : EU0;
    const unsigned short* EVc = (s & 1) ? EV1 : EV0;
    unsigned short* EUn = (s & 1) ? EU0 : EU1;
    unsigned short* EVn = (s & 1) ? EV0 : EV1;
    half8 A[4], B[4];
#pragma unroll
    for (int mt = 0; mt < 4; ++mt) A[mt] = ldsh8(&EUc[(wj + mt*16)*32 + inner]);
#pragma unroll
    for (int nt = 0; nt < 4; ++nt) B[nt] = ldsh8(&EVc[(wk + nt*16)*32 + inner]);
    if (s < 7)
      stage_slab(tid, (s+1)*32, usc, vscR, vrow, rmin, nssU, lzU, nssV, lzV, EUn, EVn);
    __builtin_amdgcn_s_setprio(1);
#pragma unroll
    for (int mt = 0; mt < 4; ++mt)
#pragma unroll
      for (int nt = 0; nt < 4; ++nt)
        acc[mt*4+nt] = __builtin_amdgcn_mfma_f32_16x16x32_f16(A[mt], B[nt], acc[mt*4+nt], 0, 0, 0);
    __builtin_amdgcn_s_setprio(0);
    __syncthreads();
  }

  // epilogue: dot with cost + coalesced NT u32x4 Gamma store (frag pairs).
  // C/D map: col=lane&15, row=(lane>>4)*4+reg
  const float* cb = cost + (size_t)bh * 65536;
  const int c8 = ((bh*2 + sb)*8 + wave) * 8;
  float part = 0.f;
#pragma unroll
  for (int mt = 0; mt < 4; ++mt) {
#pragma unroll
    for (int nt2 = 0; nt2 < 2; ++nt2) {
      const int colA = wk + nt2*32 + m;
      const int rowb = j0 + wj + mt*16 + q*4;
      f32x4 a0 = acc[mt*4 + 2*nt2];
      f32x4 a1 = acc[mt*4 + 2*nt2 + 1];
      const float* cr0 = cb + (size_t)rowb*256;
      part += a0.x*cr0[colA]        + a0.y*cr0[256 + colA]
            + a0.z*cr0[512 + colA]  + a0.w*cr0[768 + colA]
            + a1.x*cr0[colA + 16]   + a1.y*cr0[256 + colA + 16]
            + a1.z*cr0[512 + colA + 16] + a1.w*cr0[768 + colA + 16];
      u32x4 pk;
      pk[0] = cvt_pk_bf16(a0.x, a0.y);
      pk[1] = cvt_pk_bf16(a0.z, a0.w);
      pk[2] = cvt_pk_bf16(a1.x, a1.y);
      pk[3] = cvt_pk_bf16(a1.z, a1.w);
      __builtin_nontemporal_store(pk, &gamma[((size_t)(c8 + mt*2 + nt2)*64 + l)*64 + lane]);
    }
  }
#pragma unroll
  for (int o = 32; o > 0; o >>= 1) part += __shfl_down(part, o, 64);
  if (lane == 0) red[wave] = part;
  __syncthreads();
  if (tid == 0) {
    float s8 = red[0]+red[1]+red[2]+red[3]+red[4]+red[5]+red[6]+red[7];
    parts[sb*1024 + bh*64 + l] = s8;
  }
}

// wsum: 512 blocks x 4 waves; each wave streams one 64KB frag-pair chunk
// (u32x4/lane per l), l-sweep staggered by chunk id.
__global__ __launch_bounds__(256) void wsum_kernel(const u32x4* __restrict__ g,
                                                   const float* __restrict__ parts,
                                                   float* __restrict__ out) {
  const int wv = threadIdx.x >> 6, lane = threadIdx.x & 63;
  const int c  = blockIdx.x * 4 + wv;             // 2048 chunks; bh uniform per block
  const int bh = c >> 7;
  __shared__ float w[64];
  if (threadIdx.x < 64) {
    float s = parts[bh*64 + lane] + parts[1024 + bh*64 + lane];
    float v = -TEMP * s * 1.4426950408889634f;    // log2-domain logits
    float mx = v;
#pragma unroll
    for (int o = 32; o > 0; o >>= 1) mx = fmaxf(mx, __shfl_xor(mx, o, 64));
    float e = fexp2(v - mx);
    float ssum = e;
#pragma unroll
    for (int o = 32; o > 0; o >>= 1) ssum += __shfl_xor(ssum, o, 64);
    w[lane] = e / ssum;
  }
  __syncthreads();
  const u32x4* gp = g + (size_t)c*4096 + lane;
  const int st = c & 63;
  float4 accA = {0.f, 0.f, 0.f, 0.f};
  float4 accB = {0.f, 0.f, 0.f, 0.f};
#pragma unroll 16
  for (int p = 0; p < 64; ++p) {
    const int l = (p + st) & 63;
    u32x4 pk = __builtin_nontemporal_load(gp + l*64);
    float wl = w[l];
    accA.x += wl * __uint_as_float(pk[0] << 16);
    accA.y += wl * __uint_as_float(pk[0] & 0xFFFF0000u);
    accA.z += wl * __uint_as_float(pk[1] << 16);
    accA.w += wl * __uint_as_float(pk[1] & 0xFFFF0000u);
    accB.x += wl * __uint_as_float(pk[2] << 16);
    accB.y += wl * __uint_as_float(pk[2] & 0xFFFF0000u);
    accB.z += wl * __uint_as_float(pk[3] << 16);
    accB.w += wl * __uint_as_float(pk[3] & 0xFFFF0000u);
  }
  const int nt2 = c & 1, mt = (c >> 1) & 3, rest = c >> 3;
  const int wave = rest & 7, sbb = (rest >> 3) & 1;
  const int m = lane & 15, q = lane >> 4;
  const int row  = sbb*128 + (wave & 1)*64 + mt*16 + q*4;
  const int colA = (wave >> 1)*64 + nt2*32 + m;
  float* ob = out + ((size_t)bh*256 + row)*256 + colA;
  __builtin_nontemporal_store(accA.x, &ob[0]);
  __builtin_nontemporal_store(accA.y, &ob[256]);
  __builtin_nontemporal_store(accA.z, &ob[512]);
  __builtin_nontemporal_store(accA.w, &ob[768]);
  __builtin_nontemporal_store(accB.x, &ob[16]);
  __builtin_nontemporal_store(accB.y, &ob[272]);
  __builtin_nontemporal_store(accB.z, &ob[528]);
  __builtin_nontemporal_store(accB.w, &ob[784]);
}

extern "C" void kernel_launch(void* const* d_in, const int* in_sizes, int n_in,
                              void* d_out, int out_size, void* d_ws, size_t ws_size,
                              hipStream_t stream) {
  (void)in_sizes; (void)n_in; (void)out_size; (void)ws_size;
  const float* X = (const float*)d_in[0];
  const float* Y = (const float*)d_in[1];
  float* out = (float*)d_out;
  float* ws  = (float*)d_ws;
  float* cost  = ws;                    // 1048576
  float* nssu  = ws   + 1048576;
  float* lziu  = nssu + 262144;
  float* nssv  = lziu + 262144;
  float* lziv  = nssv + 262144;
  float* parts = lziv + 262144;         // 2048 (written, not accumulated)
  u32x4* gamma = (u32x4*)(parts + 2048);// 2048 chunks x 64 l x 64 lanes x 16B = 134MB

  prep_kernel <<<dim3(3072),      256, 0, stream>>>(X, Y, cost, nssu, lziu, nssv, lziv);
  pass1_kernel<<<dim3(2, 64, 16), 512, 0, stream>>>(X, Y, cost, nssu, lziu, nssv, lziv,
                                                    parts, gamma);
  wsum_kernel <<<dim3(512),       256, 0, stream>>>(gamma, parts, out);
}

// Round 7
// 164.243 us; speedup vs baseline: 1.0856x; 1.0856x over previous
//
#include <hip/hip_runtime.h>
#include <math.h>

#define INV_TAU 1000.0f
#define TEMP    0.1f
#define CEXP    -1442.6950408889634f   // -1000 * log2(e)
#define SQRTC   37.98283767f           // sqrt(1000 * log2(e))

// Problem: B=2,H=8 -> BH=16; N=256; L=64.  X,Y: [BH,256,64] f32. out: [BH,256,256] f32.
//
// Round 17: full revert to the round-0 structure (best measured: 162.8us) --
// strip blocks (128j x 256k, 512 thr, 8 waves, acc[16]/wave, 2 blocks/CU),
// scalar 3-op exp entries, bf16r epilogue pack, u32x2 NT gamma, 1024-block
// wsum. Single isolated addition: s_setprio(1) around the MFMA cluster (T5;
// pays in independent-multi-block regimes like this one -- 2 blocks/CU with
// staging/MFMA role diversity -- measured +4-7% in the analogous attn case).
// All other session deltas are dropped (each measured neutral-to-negative).
//
// ws (floats): cost[1048576] | nssu|lziu|nssv|lziv (262144 ea) |
//              parts[2048] | gamma u32x2[4096*64*64] (134MB)

typedef __attribute__((ext_vector_type(8))) _Float16 half8;
typedef __attribute__((ext_vector_type(8))) short short8;
typedef __attribute__((ext_vector_type(4))) float f32x4;
typedef __attribute__((ext_vector_type(2))) unsigned int u32x2;

__device__ __forceinline__ float fexp2(float x) { return __builtin_amdgcn_exp2f(x); }

__device__ __forceinline__ half8 ldsh8(const unsigned short* p) {
  return __builtin_bit_cast(half8, *(const short8*)p);
}

__device__ __forceinline__ unsigned bf16r(float f) {   // bf16 RNE, low 16 bits
  unsigned u = __float_as_uint(f);
  return (u + 0x7FFFu + ((u >> 16) & 1u)) >> 16;
}

// swizzled short-offset of (row, oct g) in a 32-short-per-row table
__device__ __forceinline__ int tswz(int row, int g) {
  return row * 32 + (((g + (row >> 1)) & 3) << 3);
}

// prep: blockIdx.x < 1024 -> cost quad-row tile; else sortz for (l, bh, X/Y).
// sortz stores nss = -SQRTC*sorted_val and lz = -log2(Z) (banded Z, tail<e^-60).
__global__ __launch_bounds__(256) void prep_kernel(const float* __restrict__ X,
                                                   const float* __restrict__ Y,
                                                   float* __restrict__ cost,
                                                   float* __restrict__ nssu, float* __restrict__ lziu,
                                                   float* __restrict__ nssv, float* __restrict__ lziv) {
  __shared__ __align__(16) float smem[256];
  const int tid = threadIdx.x;
  if (blockIdx.x < 1024) {
    const int jq = blockIdx.x & 63, bh = blockIdx.x >> 6;
    const int j0 = jq * 4;
    smem[tid] = X[((size_t)bh*256 + j0 + (tid >> 6))*64 + (tid & 63)];
    __syncthreads();
    const float4* yp = (const float4*)(Y + ((size_t)bh*256 + tid)*64);
    float dot[4] = {0.f,0.f,0.f,0.f}, x2[4] = {0.f,0.f,0.f,0.f}, y2 = 0.f;
#pragma unroll
    for (int t = 0; t < 16; ++t) {
      float4 yv = yp[t];
      y2 += yv.x*yv.x + yv.y*yv.y + yv.z*yv.z + yv.w*yv.w;
#pragma unroll
      for (int r = 0; r < 4; ++r) {
        float4 xv = ((const float4*)(smem + r*64))[t];
        dot[r] += xv.x*yv.x + xv.y*yv.y + xv.z*yv.z + xv.w*yv.w;
        x2[r]  += xv.x*xv.x + xv.y*xv.y + xv.z*xv.z + xv.w*xv.w;
      }
    }
#pragma unroll
    for (int r = 0; r < 4; ++r) {
      float c = x2[r] + y2 - 2.f*dot[r];
      cost[((size_t)bh*256 + j0 + r)*256 + tid] = sqrtf(fmaxf(c, 1e-12f));
    }
  } else {
    const int idx = blockIdx.x - 1024;
    const int l = idx & 63, bh = (idx >> 6) & 15, uv = idx >> 10;
    const float* S = uv ? Y : X;
    float* so = uv ? nssv : nssu;
    float* zo = uv ? lziv : lziu;
    float v = S[((size_t)bh*256 + tid)*64 + l];
#pragma unroll
    for (int k = 2; k <= 256; k <<= 1) {
#pragma unroll
      for (int j = k >> 1; j > 0; j >>= 1) {
        float o;
        if (j >= 64) {
          smem[tid] = v; __syncthreads();
          o = smem[tid ^ j]; __syncthreads();
        } else {
          o = __shfl_xor(v, j, 64);
        }
        const bool up    = ((tid & k) == 0);
        const bool lower = ((tid & j) == 0);
        float mn = fminf(v, o), mx = fmaxf(v, o);
        v = (up == lower) ? mn : mx;
      }
    }
    smem[tid] = v; __syncthreads();
    const int jc = 255 - tid;
    const float sv = smem[jc];
    const int lo = jc > 48 ? jc - 48 : 0;
    const int hi = jc < 207 ? jc + 48 : 255;
    float z = 0.f;
    for (int jj = lo; jj <= hi; ++jj) { float d = smem[jj] - sv; z += fexp2(d*d*CEXP); }
    const int base = (bh*64 + l)*256 + tid;
    so[base] = -SQRTC * sv; zo[base] = -__log2f(z);
  }
}

// stage one 32-i slab (512 threads): EU (128 rows): thread t -> row t&127,
// oct t>>7 (8 entries). EV (256 rows): row t&255, octs (t>>8)*2+{0,1} (16).
// Entry: d = usc + nss_i; e = exp2(fma(-d,d,lz_i)).  3 VALU ops/entry.
__device__ __forceinline__ void stage_slab(int t, int ib, float usc, float vsc,
                                           const float* __restrict__ nssU, const float* __restrict__ lzU,
                                           const float* __restrict__ nssV, const float* __restrict__ lzV,
                                           unsigned short* __restrict__ EU,
                                           unsigned short* __restrict__ EV) {
  {
    const int r = t & 127, g = t >> 7;
    const int i0 = ib + (g << 3);
    float e[8];
#pragma unroll
    for (int ii = 0; ii < 8; ++ii) {
      float d = usc + nssU[i0 + ii];
      e[ii] = fexp2(fmaf(-d, d, lzU[i0 + ii]));
    }
    uint4 w;
    w.x = __builtin_bit_cast(unsigned, __builtin_amdgcn_cvt_pkrtz(e[0], e[1]));
    w.y = __builtin_bit_cast(unsigned, __builtin_amdgcn_cvt_pkrtz(e[2], e[3]));
    w.z = __builtin_bit_cast(unsigned, __builtin_amdgcn_cvt_pkrtz(e[4], e[5]));
    w.w = __builtin_bit_cast(unsigned, __builtin_amdgcn_cvt_pkrtz(e[6], e[7]));
    *(uint4*)&EU[tswz(r, g)] = w;
  }
  {
    const int r = t & 255;
    const int gp = (t >> 8) << 1;
#pragma unroll
    for (int gg = 0; gg < 2; ++gg) {
      const int i0 = ib + ((gp + gg) << 3);
      float e[8];
#pragma unroll
      for (int ii = 0; ii < 8; ++ii) {
        float d = vsc + nssV[i0 + ii];
        e[ii] = fexp2(fmaf(-d, d, lzV[i0 + ii]));
      }
      uint4 w;
      w.x = __builtin_bit_cast(unsigned, __builtin_amdgcn_cvt_pkrtz(e[0], e[1]));
      w.y = __builtin_bit_cast(unsigned, __builtin_amdgcn_cvt_pkrtz(e[2], e[3]));
      w.z = __builtin_bit_cast(unsigned, __builtin_amdgcn_cvt_pkrtz(e[4], e[5]));
      w.w = __builtin_bit_cast(unsigned, __builtin_amdgcn_cvt_pkrtz(e[6], e[7]));
      *(uint4*)&EV[tswz(r, gp + gg)] = w;
    }
  }
}

// Pass 1: per (strip sb, l, bh): 128j x 256k Gamma strip via pipelined fp16
// MFMA (8 waves, 64x64 wave tiles, acc[16]); dot with cost -> parts; Gamma
// bf16 NT-store fragment-linear [group][l][lane].
__global__ __launch_bounds__(512, 4) void pass1_kernel(
    const float* __restrict__ X, const float* __restrict__ Y,
    const float* __restrict__ cost,
    const float* __restrict__ nssu, const float* __restrict__ lziu,
    const float* __restrict__ nssv, const float* __restrict__ lziv,
    float* __restrict__ parts, u32x2* __restrict__ gamma) {
  const int sb = blockIdx.x, l = blockIdx.y, bh = blockIdx.z;
  const int j0 = sb * 128;
  const int tid = threadIdx.x, wave = tid >> 6, lane = tid & 63;
  const int wj = (wave & 1) * 64, wk = (wave >> 1) * 64;
  const int m = lane & 15, q = lane >> 4;
  const int inner = m*32 + (((q + (m >> 1)) & 3) << 3);

  __shared__ float nssU[256], lzU[256], nssV[256], lzV[256];
  __shared__ __align__(16) unsigned short EU0[128*32], EU1[128*32];
  __shared__ __align__(16) unsigned short EV0[256*32], EV1[256*32];
  __shared__ float red[8];
  // LDS: 4KB + 16KB + 32KB = 52.2KB -> 2 blocks/CU x 8 waves = 4 waves/SIMD

  const int lb = (bh*64 + l)*256;
  const float usc = SQRTC * X[((size_t)bh*256 + j0 + (tid & 127))*64 + l];
  const float vsc = SQRTC * Y[((size_t)bh*256 + (tid & 255))*64 + l];
  if (tid < 256) { nssU[tid] = nssu[lb + tid]; lzU[tid] = lziu[lb + tid]; }
  else { const int t2 = tid - 256; nssV[t2] = nssv[lb + t2]; lzV[t2] = lziv[lb + t2]; }

  f32x4 acc[16];
#pragma unroll
  for (int t = 0; t < 16; ++t) acc[t] = (f32x4){0.f, 0.f, 0.f, 0.f};

  __syncthreads();
  stage_slab(tid, 0, usc, vsc, nssU, lzU, nssV, lzV, EU0, EV0);
  __syncthreads();
#pragma unroll 1
  for (int s = 0; s < 8; ++s) {
    const unsigned short* EUc = (s & 1) ? EU1 : EU0;
    const unsigned short* EVc = (s & 1) ? EV1 : EV0;
    unsigned short* EUn = (s & 1) ? EU0 : EU1;
    unsigned short* EVn = (s & 1) ? EV0 : EV1;
    half8 A[4], B[4];
#pragma unroll
    for (int mt = 0; mt < 4; ++mt) A[mt] = ldsh8(&EUc[(wj + mt*16)*32 + inner]);
#pragma unroll
    for (int nt = 0; nt < 4; ++nt) B[nt] = ldsh8(&EVc[(wk + nt*16)*32 + inner]);
    if (s < 7)
      stage_slab(tid, (s+1)*32, usc, vsc, nssU, lzU, nssV, lzV, EUn, EVn);
    __builtin_amdgcn_s_setprio(1);
#pragma unroll
    for (int mt = 0; mt < 4; ++mt)
#pragma unroll
      for (int nt = 0; nt < 4; ++nt)
        acc[mt*4+nt] = __builtin_amdgcn_mfma_f32_16x16x32_f16(A[mt], B[nt], acc[mt*4+nt], 0, 0, 0);
    __builtin_amdgcn_s_setprio(0);
    __syncthreads();
  }

  // epilogue: dot with cost + coalesced NT bf16 Gamma store.
  // C/D map: col=lane&15, row=(lane>>4)*4+reg
  const float* cb = cost + (size_t)bh * 65536;
  const int gbase = ((bh*2 + sb)*8 + wave) * 16;
  float part = 0.f;
#pragma unroll
  for (int mt = 0; mt < 4; ++mt) {
#pragma unroll
    for (int nt = 0; nt < 4; ++nt) {
      const int col  = wk + nt*16 + m;
      const int rowb = j0 + wj + mt*16 + q*4;
      f32x4 a = acc[mt*4 + nt];
      part += a.x*cb[(size_t)(rowb+0)*256 + col] + a.y*cb[(size_t)(rowb+1)*256 + col]
            + a.z*cb[(size_t)(rowb+2)*256 + col] + a.w*cb[(size_t)(rowb+3)*256 + col];
      u32x2 pk;
      pk.x = bf16r(a.x) | (bf16r(a.y) << 16);
      pk.y = bf16r(a.z) | (bf16r(a.w) << 16);
      __builtin_nontemporal_store(pk, &gamma[((size_t)(gbase + mt*4 + nt)*64 + l)*64 + lane]);
    }
  }
#pragma unroll
  for (int o = 32; o > 0; o >>= 1) part += __shfl_down(part, o, 64);
  if (lane == 0) red[wave] = part;
  __syncthreads();
  if (tid == 0) {
    float s8 = red[0]+red[1]+red[2]+red[3]+red[4]+red[5]+red[6]+red[7];
    parts[sb*1024 + bh*64 + l] = s8;
  }
}

// wsum: per block, recompute softmax weights from the 2 swds partials, then
// out = sum_l w_l * Gamma_l (each wave NT-streams one 32KB fragment-linear chunk).
__global__ __launch_bounds__(256) void wsum_kernel(const u32x2* __restrict__ g,
                                                   const float* __restrict__ parts,
                                                   float* __restrict__ out) {
  const int wv = threadIdx.x >> 6, lane = threadIdx.x & 63;
  const int bh = blockIdx.x >> 6;                 // 64 blocks per bh (uniform)
  __shared__ float w[64];
  if (wv == 0) {
    float s = parts[bh*64 + lane] + parts[1024 + bh*64 + lane];
    float v = -TEMP * s * 1.4426950408889634f;    // log2-domain logits
    float mx = v;
#pragma unroll
    for (int o = 32; o > 0; o >>= 1) mx = fmaxf(mx, __shfl_xor(mx, o, 64));
    float e = fexp2(v - mx);
    float ssum = e;
#pragma unroll
    for (int o = 32; o > 0; o >>= 1) ssum += __shfl_xor(ssum, o, 64);
    w[lane] = e / ssum;
  }
  __syncthreads();
  const int group = blockIdx.x * 4 + wv;
  const u32x2* gp = g + (size_t)group*4096 + lane;
  float4 acc = {0.f, 0.f, 0.f, 0.f};
#pragma unroll 8
  for (int l = 0; l < 64; ++l) {
    u32x2 pk = __builtin_nontemporal_load(gp + l*64);
    float wl = w[l];
    acc.x += wl * __uint_as_float(pk.x << 16);
    acc.y += wl * __uint_as_float(pk.x & 0xFFFF0000u);
    acc.z += wl * __uint_as_float(pk.y << 16);
    acc.w += wl * __uint_as_float(pk.y & 0xFFFF0000u);
  }
  const int frag = group & 15;
  const int idx  = group >> 4;                    // (bh*2+sb)*8 + wave
  const int wave = idx & 7, sbb = (idx >> 3) & 1;
  const int mt = frag >> 2, nt = frag & 3;
  const int m = lane & 15, q = lane >> 4;
  const int row = sbb*128 + (wave & 1)*64 + mt*16 + q*4;
  const int col = (wave >> 1)*64 + nt*16 + m;
  float* ob = out + ((size_t)bh*256 + row)*256 + col;
  __builtin_nontemporal_store(acc.x, &ob[0]);
  __builtin_nontemporal_store(acc.y, &ob[256]);
  __builtin_nontemporal_store(acc.z, &ob[512]);
  __builtin_nontemporal_store(acc.w, &ob[768]);
}

extern "C" void kernel_launch(void* const* d_in, const int* in_sizes, int n_in,
                              void* d_out, int out_size, void* d_ws, size_t ws_size,
                              hipStream_t stream) {
  (void)in_sizes; (void)n_in; (void)out_size; (void)ws_size;
  const float* X = (const float*)d_in[0];
  const float* Y = (const float*)d_in[1];
  float* out = (float*)d_out;
  float* ws  = (float*)d_ws;
  float* cost  = ws;                    // 1048576
  float* nssu  = ws   + 1048576;
  float* lziu  = nssu + 262144;
  float* nssv  = lziu + 262144;
  float* lziv  = nssv + 262144;
  float* parts = lziv + 262144;         // 2048 (written, not accumulated)
  u32x2* gamma = (u32x2*)(parts + 2048);// 4096 groups x 64 l x 64 lanes x 8B = 134MB

  prep_kernel <<<dim3(3072),      256, 0, stream>>>(X, Y, cost, nssu, lziu, nssv, lziv);
  pass1_kernel<<<dim3(2, 64, 16), 512, 0, stream>>>(X, Y, cost, nssu, lziu, nssv, lziv,
                                                    parts, gamma);
  wsum_kernel <<<dim3(1024),      256, 0, stream>>>(gamma, parts, out);
}